// Round 11
// baseline (1053.437 us; speedup 1.0000x reference)
//
#include <hip/hip_runtime.h>

#define NROWS   131072
#define INDIM   512
#define HIDD    128
#define KCB     256
#define RPB     64    // rows per block
#define THREADS 256

// ---- d_ws layout (32-bit word offsets) ----
#define OFF_A     0u        // 3*128*256 = 98304 : folded codebook matrices
#define OFF_CV    98304u    // 3*256            : folded bias terms
#define OFF_LOG   99072u    // 131072           : logits
#define OFF_HIST  230144u   // 65536            : top-16-bit histogram
#define OFF_META  295680u   // 16               : cntA, cntB, p, Sp
#define OFF_LISTA 295696u   // 64*2
#define OFF_LISTB 295824u   // 2048*2
#define LISTB_CAP 2048u

__device__ __forceinline__ unsigned order_key(float f) {
    unsigned u = __float_as_uint(f);
    return u ^ ((u & 0x80000000u) ? 0xFFFFFFFFu : 0x80000000u);
}

// ---------------------------------------------------------------------------
// Precompute A_c[j][k], cv_c[k]; zero hist+meta.
// ---------------------------------------------------------------------------
__global__ __launch_bounds__(256) void vq_precompute(
    const float* __restrict__ Wm, const float* __restrict__ bm,
    const float* __restrict__ Wt, const float* __restrict__ bt,
    const float* __restrict__ Wp, const float* __restrict__ bp,
    const float* __restrict__ cbm, const float* __restrict__ cbt, const float* __restrict__ cbp,
    float* __restrict__ A, float* __restrict__ cv, unsigned* __restrict__ hist)
{
    for (unsigned i = blockIdx.x * 256u + threadIdx.x; i < 65536u + 16u; i += 24u * 256u)
        hist[i] = 0u;

    const int c  = blockIdx.x >> 3;
    const int jg = (blockIdx.x & 7) * 16;
    const float* W  = (c == 0) ? Wm  : (c == 1) ? Wt  : Wp;
    const float* bb = (c == 0) ? bm  : (c == 1) ? bt  : bp;
    const float* cb = (c == 0) ? cbm : (c == 1) ? cbt : cbp;
    const int k = threadIdx.x;
    const float4* cbr = (const float4*)(cb + (size_t)k * HIDD);
    float s = 0.f;
    for (int d = 0; d < HIDD / 4; ++d) {
        float4 x = cbr[d];
        s += x.x * x.x + x.y * x.y + x.z * x.z + x.w * x.w;
    }
    const float rn = 1.f / fmaxf(sqrtf(s), 1e-12f);
    for (int j = jg; j < jg + 16; ++j) {
        const float4* wr = (const float4*)(W + (size_t)j * HIDD);
        float acc = 0.f;
        for (int d = 0; d < HIDD / 4; ++d) {
            float4 x = cbr[d]; float4 w = wr[d];
            acc += x.x * w.x + x.y * w.y + x.z * w.z + x.w * w.w;
        }
        A[((size_t)c * HIDD + j) * KCB + k] = acc * rn;
    }
    if (jg == 0) {
        const float4* br = (const float4*)bb;
        float acc = 0.f;
        for (int d = 0; d < HIDD / 4; ++d) {
            float4 x = cbr[d]; float4 w = br[d];
            acc += x.x * w.x + x.y * w.y + x.z * w.z + x.w * w.w;
        }
        cv[(size_t)c * KCB + k] = acc * rn;
    }
}

// ---------------------------------------------------------------------------
// Main fused kernel, BROADCAST-tile layout:
//   rows <- tx = t&15 (rows 4*tx..4*tx+3), cols <- ty = t>>4.
//   A wave has only 4 distinct ty values -> every LDS B-read has 4 distinct
//   addresses across 64 lanes -> LDS same-address broadcast makes B nearly
//   free (bytes/instr 4-16x lower). All B operands staged via LDS (the regime
//   where the allocator grants registers: r1 got 80 VGPR for this acc shape;
//   global-B loops were clamped to 56-64 in r5/7/8/10).
// LDS exactly 40 KiB: T[128][64] 32 KiB (h0-staging aliased into T in ph1)
//   + S 8 KiB (B chunks / argmin-reduce / wsv) -> 4 blocks/CU = 4 waves/SIMD.
// Per-wave issue rate is ~29%/wave (measured constant r1/r2/r9) -> ~4x0.29
//   => VALU near saturation; LDS pipe ~390k cyc/CU < 721k FMA floor.
// ---------------------------------------------------------------------------
__global__ __launch_bounds__(THREADS, 4) void vq_main(
    const float* __restrict__ h0, const float* __restrict__ W1, const float* __restrict__ bias1,
    const float* __restrict__ W2, const float* __restrict__ bias2,
    const float* __restrict__ Amat, const float* __restrict__ cv, const float* __restrict__ wsv,
    int* __restrict__ codes, float* __restrict__ logits, unsigned* __restrict__ hist)
{
    __shared__ float T[HIDD * RPB];  // 32 KiB [k][row]; first 4 KiB = ph1 h0 staging alias
    __shared__ float S[2048];        // 8 KiB: B chunks / argmin reduce / wsv

    const int t   = threadIdx.x;
    const int tx  = t & 15;          // row group: rows 4*tx .. 4*tx+3
    const int tyv = t >> 4;          // col group: 0..15
    const int r4  = 4 * tx;
    const int row0 = blockIdx.x * RPB;
    float4* S4 = (float4*)S;

    // ---------------- phase 1: a1 = relu(h0 @ W1 + b1) -> acc -> T[k][row]
    {
        float acc[4][8] = {};
        const int srow = t >> 2;            // 0..63
        const int sq   = (t & 3) * 4;       // k-offsets {0,4,8,12}
        const float* hp = h0 + (size_t)(row0 + srow) * INDIM + sq;
        float4 ha = *(const float4*)hp;
        float* Hst = T;                      // [16k][64row] = 4 KiB alias
        const float4* W14 = (const float4*)W1;
        for (int kc = 0; kc < INDIM; kc += 16) {
            float4 w0 = W14[kc * 32 + t];        // W1 chunk [16k][128] flat
            float4 w1 = W14[kc * 32 + t + 256];
            __syncthreads();                     // prev chunk consumed
            Hst[(sq + 0) * RPB + srow] = ha.x;
            Hst[(sq + 1) * RPB + srow] = ha.y;
            Hst[(sq + 2) * RPB + srow] = ha.z;
            Hst[(sq + 3) * RPB + srow] = ha.w;
            S4[t]       = w0;
            S4[t + 256] = w1;
            if (kc + 16 < INDIM) ha = *(const float4*)(hp + kc + 16);
            __syncthreads();                     // staging ready
            #pragma unroll
            for (int k = 0; k < 16; ++k) {
                float4 a0 = *(const float4*)&Hst[k * RPB + r4];       // 16 distinct/wave
                float4 b0 = S4[k * 32 + 2 * tyv];                     // 4 distinct/wave
                float4 b1 = S4[k * 32 + 2 * tyv + 1];
                float aa[4] = {a0.x, a0.y, a0.z, a0.w};
                float bb[8] = {b0.x, b0.y, b0.z, b0.w, b1.x, b1.y, b1.z, b1.w};
                #pragma unroll
                for (int r = 0; r < 4; ++r)
                    #pragma unroll
                    for (int j = 0; j < 8; ++j)
                        acc[r][j] = fmaf(aa[r], bb[j], acc[r][j]);
            }
        }
        __syncthreads();                         // staging reads done; T writable
        float4 bv0 = *(const float4*)&bias1[8 * tyv];
        float4 bv1 = *(const float4*)&bias1[8 * tyv + 4];
        float ba[8] = {bv0.x, bv0.y, bv0.z, bv0.w, bv1.x, bv1.y, bv1.z, bv1.w};
        #pragma unroll
        for (int j = 0; j < 8; ++j) {
            const int c = 8 * tyv + j;
            float4 v;
            v.x = fmaxf(acc[0][j] + ba[j], 0.f);
            v.y = fmaxf(acc[1][j] + ba[j], 0.f);
            v.z = fmaxf(acc[2][j] + ba[j], 0.f);
            v.w = fmaxf(acc[3][j] + ba[j], 0.f);
            *(float4*)&T[c * RPB + r4] = v;
        }
    }
    __syncthreads();

    // ---------------- phase 2: H = relu(a1 @ W2 + b2) -> T (in place)
    {
        float acc[4][8] = {};
        const float4* W24 = (const float4*)W2;
        for (int kc = 0; kc < HIDD; kc += 16) {
            float4 w0 = W24[kc * 32 + t];
            float4 w1 = W24[kc * 32 + t + 256];
            __syncthreads();                     // prev chunk's S reads done
            S4[t]       = w0;
            S4[t + 256] = w1;
            __syncthreads();
            #pragma unroll
            for (int k = 0; k < 16; ++k) {
                float4 a0 = *(const float4*)&T[(kc + k) * RPB + r4];
                float4 b0 = S4[k * 32 + 2 * tyv];
                float4 b1 = S4[k * 32 + 2 * tyv + 1];
                float aa[4] = {a0.x, a0.y, a0.z, a0.w};
                float bb[8] = {b0.x, b0.y, b0.z, b0.w, b1.x, b1.y, b1.z, b1.w};
                #pragma unroll
                for (int r = 0; r < 4; ++r)
                    #pragma unroll
                    for (int j = 0; j < 8; ++j)
                        acc[r][j] = fmaf(aa[r], bb[j], acc[r][j]);
            }
        }
        __syncthreads();                         // all a1 reads done before overwrite
        float4 bv0 = *(const float4*)&bias2[8 * tyv];
        float4 bv1 = *(const float4*)&bias2[8 * tyv + 4];
        float ba[8] = {bv0.x, bv0.y, bv0.z, bv0.w, bv1.x, bv1.y, bv1.z, bv1.w};
        #pragma unroll
        for (int j = 0; j < 8; ++j) {
            const int c = 8 * tyv + j;
            float4 v;
            v.x = fmaxf(acc[0][j] + ba[j], 0.f);
            v.y = fmaxf(acc[1][j] + ba[j], 0.f);
            v.z = fmaxf(acc[2][j] + ba[j], 0.f);
            v.w = fmaxf(acc[3][j] + ba[j], 0.f);
            *(float4*)&T[c * RPB + r4] = v;
        }
    }
    // (ph3's first staging barrier orders these T writes before FMA reads)

    // ---------------- phase 3: sims = H @ A_c (+cv_c), row argmin.
    // Thread cols = 16*tyv..16*tyv+15 (acc[4][16]); A chunks [8k][256] in S.
    for (int cbk = 0; cbk < 3; ++cbk) {
        float acc[4][16] = {};
        const float4* Ab4 = (const float4*)(Amat + (size_t)cbk * HIDD * KCB);
        for (int kc = 0; kc < HIDD; kc += 8) {
            float4 s0 = Ab4[kc * 64 + t];        // [8k][256] flat chunk
            float4 s1 = Ab4[kc * 64 + t + 256];
            __syncthreads();                     // prev S use done (stage/reduce)
            S4[t]       = s0;
            S4[t + 256] = s1;
            __syncthreads();                     // staging ready
            #pragma unroll
            for (int k = 0; k < 8; ++k) {
                float4 a0 = *(const float4*)&T[(kc + k) * RPB + r4];
                float aa[4] = {a0.x, a0.y, a0.z, a0.w};
                #pragma unroll
                for (int i = 0; i < 4; ++i) {
                    float4 bv = S4[k * 64 + 4 * tyv + i];   // 4 distinct/wave
                    float bb[4] = {bv.x, bv.y, bv.z, bv.w};
                    #pragma unroll
                    for (int r = 0; r < 4; ++r)
                        #pragma unroll
                        for (int j = 0; j < 4; ++j)
                            acc[r][i * 4 + j] = fmaf(aa[r], bb[j], acc[r][i * 4 + j]);
                }
            }
        }
        // per-thread argmin over its 16 ascending cols
        float mv[4] = {3.4e38f, 3.4e38f, 3.4e38f, 3.4e38f};
        int   mi[4] = {0, 0, 0, 0};
        #pragma unroll
        for (int i = 0; i < 4; ++i) {
            float4 cvv = *(const float4*)&cv[cbk * KCB + 16 * tyv + 4 * i];
            float ca[4] = {cvv.x, cvv.y, cvv.z, cvv.w};
            #pragma unroll
            for (int j = 0; j < 4; ++j) {
                const int c = 16 * tyv + 4 * i + j;     // ascending within thread
                #pragma unroll
                for (int r = 0; r < 4; ++r) {
                    float v = acc[r][i * 4 + j] + ca[j];
                    if (v < mv[r]) { mv[r] = v; mi[r] = c; }   // strict <: earliest wins
                }
            }
        }
        // cross-wave reduce via S (free after last chunk's barrier pair)
        __syncthreads();                         // last chunk FMA reads done
        int* Si = (int*)S;
        #pragma unroll
        for (int r = 0; r < 4; ++r) {
            S[tyv * RPB + r4 + r]         = mv[r];
            Si[1024 + tyv * RPB + r4 + r] = mi[r];
        }
        __syncthreads();
        if (t < RPB) {
            float bv = S[t]; int bi = Si[1024 + t];
            #pragma unroll
            for (int w = 1; w < 16; ++w) {       // ty ascending = col-blocks ascending
                float v = S[w * RPB + t]; int i2 = Si[1024 + w * RPB + t];
                if (v < bv || (v == bv && i2 < bi)) { bv = v; bi = i2; }
            }
            codes[(size_t)(row0 + t) * 3 + cbk] = bi;
        }
        // next cb's staging barrier orders these S reads before overwrite
    }

    // ---------------- phase 4: logits + global histogram of order keys
    __syncthreads();                             // codes-reduce reads of S done
    if (t < HIDD) S[t] = wsv[t];
    __syncthreads();
    if (t < RPB) {
        float s = 0.f;
        #pragma unroll 8
        for (int k = 0; k < HIDD; ++k) s = fmaf(T[k * RPB + t], S[k], s);
        logits[row0 + t] = s;
        atomicAdd(&hist[order_key(s) >> 16], 1u);
    }
}

// ---------------------------------------------------------------------------
// Find cutoff bin p: (# elements in bins > p) < 32 <= (# in bins >= p)
// ---------------------------------------------------------------------------
__global__ __launch_bounds__(1024) void vq_findp(const unsigned* __restrict__ hist,
                                                 unsigned* __restrict__ meta)
{
    __shared__ unsigned Tb[1024];
    __shared__ unsigned sIg, sPg;
    const int t = threadIdx.x;
    unsigned s = 0;
    const uint4* hv = (const uint4*)(hist + (size_t)t * 64);
    for (int j = 0; j < 16; ++j) { uint4 h = hv[j]; s += h.x + h.y + h.z + h.w; }
    Tb[t] = s;
    __syncthreads();
    for (int d = 1; d < 1024; d <<= 1) {           // inclusive suffix sum
        unsigned v = (t + d < 1024) ? Tb[t + d] : 0u;
        __syncthreads();
        Tb[t] += v;
        __syncthreads();
    }
    const unsigned Ti = Tb[t];
    const unsigned P  = Ti - s;
    if (P < 32u && Ti >= 32u) { sIg = (unsigned)t; sPg = P; }
    __syncthreads();
    const int ig = (int)sIg;
    const unsigned Pg = sPg;
    if (t < 64) {
        unsigned c = hist[ig * 64 + t];
        unsigned Tw = c;
        #pragma unroll
        for (int d = 1; d < 64; d <<= 1) {
            unsigned v = __shfl_down(Tw, d);
            if (t + d < 64) Tw += v;
        }
        unsigned Pl = Pg + Tw - c;
        if (Pl < 32u && Pl + c >= 32u) { meta[2] = (unsigned)(ig * 64 + t); meta[3] = Pl; }
    }
}

// ---------------------------------------------------------------------------
// Collect candidates: bin > p -> list A (all selected), bin == p -> list B
// ---------------------------------------------------------------------------
__global__ __launch_bounds__(256) void vq_collect(
    const float* __restrict__ logits, unsigned* __restrict__ meta,
    unsigned* __restrict__ listA, unsigned* __restrict__ listB)
{
    const int i = blockIdx.x * 256 + threadIdx.x;
    const unsigned key = order_key(logits[i]);
    const unsigned p = meta[2];
    const unsigned b = key >> 16;
    if (b > p) {
        unsigned idx = atomicAdd(&meta[0], 1u);
        if (idx < 64u) { listA[2 * idx] = key; listA[2 * idx + 1] = (unsigned)i; }
    } else if (b == p) {
        unsigned idx = atomicAdd(&meta[1], 1u);
        if (idx < LISTB_CAP) { listB[2 * idx] = key; listB[2 * idx + 1] = (unsigned)i; }
    }
}

// ---------------------------------------------------------------------------
// Parallel ordered selection of 32 (value desc, index asc — lax.top_k)
// ---------------------------------------------------------------------------
__global__ __launch_bounds__(256) void vq_final(
    const unsigned* __restrict__ meta,
    const unsigned* __restrict__ listA, const unsigned* __restrict__ listB,
    const int* __restrict__ codes,
    int* __restrict__ outki, int* __restrict__ outsel)
{
    __shared__ unsigned Ks[64 + LISTB_CAP];
    __shared__ unsigned Is[64 + LISTB_CAP];
    __shared__ int sel[32];
    const int t = threadIdx.x;
    const unsigned nAv = meta[0];
    const unsigned nBv = meta[1];
    const int nA = (nAv > 64u) ? 64 : (int)nAv;
    const int nB = (nBv > LISTB_CAP) ? (int)LISTB_CAP : (int)nBv;
    const int n  = nA + nB;
    for (int j = t; j < n; j += 256) {
        if (j < nA) { Ks[j] = listA[2 * j]; Is[j] = listA[2 * j + 1]; }
        else        { int jj = j - nA; Ks[j] = listB[2 * jj]; Is[j] = listB[2 * jj + 1]; }
    }
    __syncthreads();
    for (int j = t; j < n; j += 256) {
        const unsigned kj = Ks[j], ij = Is[j];
        int rank = 0;
        for (int m = 0; m < n; ++m) {
            const unsigned km = Ks[m], im = Is[m];
            rank += (km > kj) || (km == kj && im < ij);
        }
        if (rank < 32) sel[rank] = (int)ij;
    }
    __syncthreads();
    if (t < 32) outki[t] = sel[t];
    if (t < 96) outsel[t] = codes[3 * sel[t / 3] + (t % 3)];
}

// ---------------------------------------------------------------------------
extern "C" void kernel_launch(void* const* d_in, const int* in_sizes, int n_in,
                              void* d_out, int out_size, void* d_ws, size_t ws_size,
                              hipStream_t stream)
{
    (void)in_sizes; (void)n_in; (void)out_size; (void)ws_size;

    const float* h0  = (const float*)d_in[0];
    const float* W1  = (const float*)d_in[1];
    const float* b1  = (const float*)d_in[2];
    const float* W2  = (const float*)d_in[3];
    const float* b2  = (const float*)d_in[4];
    const float* Wm  = (const float*)d_in[5];
    const float* bm  = (const float*)d_in[6];
    const float* Wt  = (const float*)d_in[7];
    const float* bt  = (const float*)d_in[8];
    const float* Wp  = (const float*)d_in[9];
    const float* bp  = (const float*)d_in[10];
    const float* cbm = (const float*)d_in[11];
    const float* cbt = (const float*)d_in[12];
    const float* cbp = (const float*)d_in[13];
    const float* wsv = (const float*)d_in[14];

    float*    wsf   = (float*)d_ws;
    unsigned* wsu   = (unsigned*)d_ws;
    float*    A     = wsf + OFF_A;
    float*    cvv   = wsf + OFF_CV;
    float*    logit = wsf + OFF_LOG;
    unsigned* hist  = wsu + OFF_HIST;
    unsigned* meta  = wsu + OFF_META;
    unsigned* listA = wsu + OFF_LISTA;
    unsigned* listB = wsu + OFF_LISTB;

    int* codes  = (int*)d_out;
    int* outki  = codes + (size_t)NROWS * 3;
    int* outsel = outki + 32;

    vq_precompute<<<24, 256, 0, stream>>>(Wm, bm, Wt, bt, Wp, bp, cbm, cbt, cbp, A, cvv, hist);
    vq_main<<<NROWS / RPB, THREADS, 0, stream>>>(h0, W1, b1, W2, b2, A, cvv, wsv, codes, logit, hist);
    vq_findp<<<1, 1024, 0, stream>>>(hist, meta);
    vq_collect<<<NROWS / 256, 256, 0, stream>>>(logit, meta, listA, listB);
    vq_final<<<1, 256, 0, stream>>>(meta, listA, listB, codes, outki, outsel);
}